// Round 2
// baseline (116.802 us; speedup 1.0000x reference)
//
#include <hip/hip_runtime.h>

#define D_MODEL 1024
#define D_STATE 16
#define BATCH   2
#define SEQ     2048
#define CHUNK   32
#define NCHUNK  (SEQ / CHUNK)   // 64
#define NGRP    (SEQ / 4)       // 512 step-groups of 4

// ---------------------------------------------------------------------------
// K1: B_t[b,l,s] = sum_d x[b,l,d] * B_w[s,d]
// Block = 256 threads = 4 waves; wave w owns s-quad w, lane owns a 16-d slice.
// B_w lives in registers; full-d reduction = in-wave xor butterfly.
// Writes bt[b][l][16]           (row-major, for k_final's uniform row loads)
// and    btg[b][l/4][s][4]      (group-interleaved, for k_scan's coalesced
//                                wave loads: 16 s x float4 = 256 B contiguous)
// ---------------------------------------------------------------------------
__global__ __launch_bounds__(256) void k_bt(const float* __restrict__ x,
                                            const float* __restrict__ Bw,
                                            float* __restrict__ bt,
                                            float* __restrict__ btg) {
    const int t    = threadIdx.x;
    const int wave = t >> 6;   // s-quad
    const int lane = t & 63;   // d-group

    float4 bw[4][4];
    const float* bwp = Bw + (wave * 4) * D_MODEL + lane * 16;
#pragma unroll
    for (int i = 0; i < 4; ++i)
#pragma unroll
        for (int k = 0; k < 4; ++k)
            bw[i][k] = *(const float4*)(bwp + i * D_MODEL + k * 4);

    const int ROWS = (BATCH * SEQ) / gridDim.x;
    const int row0 = blockIdx.x * ROWS;
    for (int r = 0; r < ROWS; ++r) {
        const int row = row0 + r;   // flat (b*SEQ + l)
        const float* xr = x + (size_t)row * D_MODEL + lane * 16;
        float4 xv[4];
#pragma unroll
        for (int k = 0; k < 4; ++k) xv[k] = *(const float4*)(xr + k * 4);

        float acc[4] = {0.f, 0.f, 0.f, 0.f};
#pragma unroll
        for (int i = 0; i < 4; ++i) {
#pragma unroll
            for (int k = 0; k < 4; ++k) {
                acc[i] += xv[k].x * bw[i][k].x;
                acc[i] += xv[k].y * bw[i][k].y;
                acc[i] += xv[k].z * bw[i][k].z;
                acc[i] += xv[k].w * bw[i][k].w;
            }
        }
#pragma unroll
        for (int m = 1; m < 64; m <<= 1) {
#pragma unroll
            for (int i = 0; i < 4; ++i) acc[i] += __shfl_xor(acc[i], m, 64);
        }
        if (lane == 0) {
            *(float4*)(bt + (size_t)row * D_STATE + wave * 4) =
                make_float4(acc[0], acc[1], acc[2], acc[3]);
            const int b = row >> 11;        // SEQ = 2048
            const int l = row & (SEQ - 1);
            float* p = btg + (((size_t)(b * NGRP + (l >> 2)) * D_STATE + wave * 4) << 2) + (l & 3);
#pragma unroll
            for (int i = 0; i < 4; ++i) p[i * 4] = acc[i];
        }
    }
}

// ---------------------------------------------------------------------------
// K2: full-sequence scan, one thread per (b,d,s). A^4-blocked Horner:
//   h_{l+4} = A^4 h_l + ((b_l A + b_{l+1}) A + b_{l+2}) A + b_{l+3}
// Reads btg (wave loads = 256 B contiguous, 4-lane broadcast per address).
// Writes carry_in[b][c][d][s] every CHUNK steps (coalesced 512 B per wave).
// No inter-thread deps, no LDS, no syncthreads.
// ---------------------------------------------------------------------------
__global__ __launch_bounds__(128) void k_scan(const float* __restrict__ btg,
                                              const float* __restrict__ logA,
                                              float* __restrict__ carry) {
    const int g = blockIdx.x * 128 + threadIdx.x;   // 0 .. B*D*S-1 = 32767
    const int s = g & 15;
    const int d = (g >> 4) & (D_MODEL - 1);
    const int b = g >> 14;

    const float A  = expf(-expf(logA[d * D_STATE + s]));
    const float A2 = A * A;
    const float A4 = A2 * A2;

    const float4* bp = (const float4*)btg + (size_t)b * NGRP * D_STATE + s;
    size_t ci = (size_t)b * NCHUNK * (D_MODEL * D_STATE) + d * D_STATE + s;

    float h = 0.f;
    for (int c = 0; c < NCHUNK; ++c) {
        carry[ci] = h;                 // carry_in for chunk c
        ci += D_MODEL * D_STATE;
#pragma unroll
        for (int gg = 0; gg < CHUNK / 4; ++gg) {
            const float4 v = bp[(size_t)(c * (CHUNK / 4) + gg) * D_STATE];
            h = h * A4 + (((v.x * A + v.y) * A + v.z) * A + v.w);
        }
    }
}

// ---------------------------------------------------------------------------
// K3: final pass. Block = (b, chunk c, d-tile of 256); thread = one d.
// Re-runs the local scan seeded with carry_in, fuses C-projection + skip.
// bt rows are wave-uniform addresses (scalar/broadcast loads); x/y coalesced.
// ---------------------------------------------------------------------------
__global__ __launch_bounds__(256) void k_final(const float* __restrict__ x,
                                               const float* __restrict__ logA,
                                               const float* __restrict__ Cw,
                                               const float* __restrict__ Dv,
                                               const float* __restrict__ bt,
                                               const float* __restrict__ carry,
                                               float* __restrict__ y) {
    const int blk = blockIdx.x;
    const int dt  = blk & 3;                  // D_MODEL/256 = 4 tiles
    const int c   = (blk >> 2) & (NCHUNK - 1);
    const int b   = blk >> 8;
    const int t   = threadIdx.x;
    const int d   = dt * 256 + t;

    float A[D_STATE], C[D_STATE], h[D_STATE];
    const float* lp = logA + (size_t)d * D_STATE;
    const float* cp = Cw + (size_t)d * D_STATE;
    const float* hp = carry + ((size_t)(b * NCHUNK + c) * D_MODEL + d) * D_STATE;
#pragma unroll
    for (int s = 0; s < D_STATE; ++s) {
        A[s] = expf(-expf(lp[s]));
        C[s] = cp[s];
        h[s] = hp[s];
    }
    const float dv = Dv[d];

    const float* btrow = bt + (size_t)(b * SEQ + c * CHUNK) * D_STATE;  // uniform
    const size_t rowbase = (size_t)(b * SEQ + c * CHUNK) * D_MODEL + d;
    const float* xp = x + rowbase;
    float*       yp = y + rowbase;

#pragma unroll 4
    for (int j = 0; j < CHUNK; ++j) {
        float acc = dv * xp[(size_t)j * D_MODEL];
#pragma unroll
        for (int s = 0; s < D_STATE; ++s) {
            h[s] = A[s] * h[s] + btrow[j * D_STATE + s];
            acc += C[s] * h[s];
        }
        yp[(size_t)j * D_MODEL] = acc;
    }
}

extern "C" void kernel_launch(void* const* d_in, const int* in_sizes, int n_in,
                              void* d_out, int out_size, void* d_ws, size_t ws_size,
                              hipStream_t stream) {
    const float* x    = (const float*)d_in[0];
    const float* logA = (const float*)d_in[1];
    const float* Bw   = (const float*)d_in[2];
    const float* Cw   = (const float*)d_in[3];
    const float* Dv   = (const float*)d_in[4];
    float* y = (float*)d_out;

    float* bt    = (float*)d_ws;                                   // B*L*S        = 65536 floats
    float* btg   = bt  + (size_t)BATCH * SEQ * D_STATE;            // B*L*S        = 65536 floats
    float* carry = btg + (size_t)BATCH * SEQ * D_STATE;            // B*Nc*D*S     = 2097152 floats

    hipLaunchKernelGGL(k_bt,    dim3(512), dim3(256), 0, stream, x, Bw, bt, btg);
    hipLaunchKernelGGL(k_scan,  dim3((BATCH * D_MODEL * D_STATE) / 128), dim3(128), 0, stream, btg, logA, carry);
    hipLaunchKernelGGL(k_final, dim3(BATCH * NCHUNK * (D_MODEL / 256)),  dim3(256), 0, stream, x, logA, Cw, Dv, bt, carry, y);
}

// Round 3
// 102.530 us; speedup vs baseline: 1.1392x; 1.1392x over previous
//
#include <hip/hip_runtime.h>

#define D_MODEL 1024
#define D_STATE 16
#define BATCH   2
#define SEQ     2048
#define CHUNK   32
#define NCHUNK  (SEQ / CHUNK)   // 64
#define NGRP    (SEQ / 4)       // 512 step-groups of 4
#define Q       8               // superblocks per sequence
#define SBLEN   (SEQ / Q)       // 256 steps per superblock
#define SBGRP   (SBLEN / 4)     // 64 float4-groups per superblock
#define SBCHK   (SBLEN / CHUNK) // 8 chunks per superblock

// ---------------------------------------------------------------------------
// K1: B_t[b,l,s] = sum_d x[b,l,d] * B_w[s,d]
// Block = 256 threads = 4 waves; wave w owns s-quad w, lane owns a 16-d slice.
// B_w lives in registers; full-d reduction = in-wave xor butterfly.
// Writes bt[b][l][16]       (row-major, for k_final's uniform row loads)
// and    btg[b][l/4][s][4]  (group-interleaved, for k_scan's coalesced loads)
// ---------------------------------------------------------------------------
__global__ __launch_bounds__(256) void k_bt(const float* __restrict__ x,
                                            const float* __restrict__ Bw,
                                            float* __restrict__ bt,
                                            float* __restrict__ btg) {
    const int t    = threadIdx.x;
    const int wave = t >> 6;   // s-quad
    const int lane = t & 63;   // d-group

    float4 bw[4][4];
    const float* bwp = Bw + (wave * 4) * D_MODEL + lane * 16;
#pragma unroll
    for (int i = 0; i < 4; ++i)
#pragma unroll
        for (int k = 0; k < 4; ++k)
            bw[i][k] = *(const float4*)(bwp + i * D_MODEL + k * 4);

    const int ROWS = (BATCH * SEQ) / gridDim.x;
    const int row0 = blockIdx.x * ROWS;
    for (int r = 0; r < ROWS; ++r) {
        const int row = row0 + r;   // flat (b*SEQ + l)
        const float* xr = x + (size_t)row * D_MODEL + lane * 16;
        float4 xv[4];
#pragma unroll
        for (int k = 0; k < 4; ++k) xv[k] = *(const float4*)(xr + k * 4);

        float acc[4] = {0.f, 0.f, 0.f, 0.f};
#pragma unroll
        for (int i = 0; i < 4; ++i) {
#pragma unroll
            for (int k = 0; k < 4; ++k) {
                acc[i] += xv[k].x * bw[i][k].x;
                acc[i] += xv[k].y * bw[i][k].y;
                acc[i] += xv[k].z * bw[i][k].z;
                acc[i] += xv[k].w * bw[i][k].w;
            }
        }
#pragma unroll
        for (int m = 1; m < 64; m <<= 1) {
#pragma unroll
            for (int i = 0; i < 4; ++i) acc[i] += __shfl_xor(acc[i], m, 64);
        }
        if (lane == 0) {
            *(float4*)(bt + (size_t)row * D_STATE + wave * 4) =
                make_float4(acc[0], acc[1], acc[2], acc[3]);
            const int b = row >> 11;        // SEQ = 2048
            const int l = row & (SEQ - 1);
            float* p = btg + (((size_t)(b * NGRP + (l >> 2)) * D_STATE + wave * 4) << 2) + (l & 3);
#pragma unroll
            for (int i = 0; i < 4; ++i) p[i * 4] = acc[i];
        }
    }
}

// ---------------------------------------------------------------------------
// K2: two-level scan. Thread = (b, d, s, q); q = superblock of 256 steps.
// Block = 256 threads: one b, 2 d's, 16 s, all 8 q (q = t>>5, ds = t&31).
//   Pass 1: scan own superblock from zero, snapshot local chunk-carries.
//   LDS:    exchange superblock finals, Horner-combine with A^256 weights
//           to get true incoming state H for own superblock.
//   Pass 2: write true carry_in[chunk] = local[k] + A^(32k) * H.
// 1024 blocks -> ~4 waves/SIMD; dep chain 256 cycles (was 2048).
// ---------------------------------------------------------------------------
__global__ __launch_bounds__(256) void k_scan(const float* __restrict__ btg,
                                              const float* __restrict__ logA,
                                              float* __restrict__ carry) {
    const int blk = blockIdx.x;
    const int b   = blk >> 9;            // 512 blocks per batch
    const int dp  = blk & 511;           // d-pair
    const int t   = threadIdx.x;
    const int q   = t >> 5;
    const int ds  = t & 31;
    const int s   = ds & 15;
    const int d   = dp * 2 + (ds >> 4);

    const float A  = expf(-expf(logA[d * D_STATE + s]));
    const float A2 = A * A,    A4 = A2 * A2;
    const float A8 = A4 * A4,  A16 = A8 * A8,  A32 = A16 * A16;
    const float A64 = A32 * A32, A128 = A64 * A64, A256 = A128 * A128;

    const float4* bp = (const float4*)btg + ((size_t)b * NGRP + q * SBGRP) * D_STATE + s;

    // Pass 1: local scan of own superblock (zero initial state)
    float localC[SBCHK];
    float h = 0.f;
#pragma unroll
    for (int k = 0; k < SBCHK; ++k) {
        localC[k] = h;
#pragma unroll
        for (int gg = 0; gg < CHUNK / 4; ++gg) {
            const float4 v = bp[(size_t)(k * (CHUNK / 4) + gg) * D_STATE];
            h = h * A4 + (((v.x * A + v.y) * A + v.z) * A + v.w);
        }
    }

    // Exchange superblock finals within block
    __shared__ float Fs[32][Q + 1];   // padded: conflict-free
    Fs[ds][q] = h;
    __syncthreads();

    // True incoming state for superblock q
    float H = 0.f;
    for (int p = 0; p < q; ++p) H = H * A256 + Fs[ds][p];

    // Pass 2: publish true chunk carries
    float fac = H;
    size_t ci = (((size_t)(b * NCHUNK + q * SBCHK)) * D_MODEL + d) * D_STATE + s;
#pragma unroll
    for (int k = 0; k < SBCHK; ++k) {
        carry[ci] = localC[k] + fac;
        fac *= A32;
        ci += (size_t)D_MODEL * D_STATE;
    }
}

// ---------------------------------------------------------------------------
// K3: final pass. Block = (b, chunk c, d-tile of 256); thread = one d.
// Re-runs the local scan seeded with carry_in, fuses C-projection + skip.
// bt rows are wave-uniform addresses (scalar/broadcast loads); x/y coalesced.
// ---------------------------------------------------------------------------
__global__ __launch_bounds__(256) void k_final(const float* __restrict__ x,
                                               const float* __restrict__ logA,
                                               const float* __restrict__ Cw,
                                               const float* __restrict__ Dv,
                                               const float* __restrict__ bt,
                                               const float* __restrict__ carry,
                                               float* __restrict__ y) {
    const int blk = blockIdx.x;
    const int dt  = blk & 3;                  // D_MODEL/256 = 4 tiles
    const int c   = (blk >> 2) & (NCHUNK - 1);
    const int b   = blk >> 8;
    const int t   = threadIdx.x;
    const int d   = dt * 256 + t;

    float A[D_STATE], C[D_STATE], h[D_STATE];
    const float* lp = logA + (size_t)d * D_STATE;
    const float* cp = Cw + (size_t)d * D_STATE;
    const float* hp = carry + ((size_t)(b * NCHUNK + c) * D_MODEL + d) * D_STATE;
#pragma unroll
    for (int s = 0; s < D_STATE; ++s) {
        A[s] = expf(-expf(lp[s]));
        C[s] = cp[s];
        h[s] = hp[s];
    }
    const float dv = Dv[d];

    const float* btrow = bt + (size_t)(b * SEQ + c * CHUNK) * D_STATE;  // uniform
    const size_t rowbase = (size_t)(b * SEQ + c * CHUNK) * D_MODEL + d;
    const float* xp = x + rowbase;
    float*       yp = y + rowbase;

#pragma unroll 4
    for (int j = 0; j < CHUNK; ++j) {
        float acc = dv * xp[(size_t)j * D_MODEL];
#pragma unroll
        for (int s = 0; s < D_STATE; ++s) {
            h[s] = A[s] * h[s] + btrow[j * D_STATE + s];
            acc += C[s] * h[s];
        }
        yp[(size_t)j * D_MODEL] = acc;
    }
}

extern "C" void kernel_launch(void* const* d_in, const int* in_sizes, int n_in,
                              void* d_out, int out_size, void* d_ws, size_t ws_size,
                              hipStream_t stream) {
    const float* x    = (const float*)d_in[0];
    const float* logA = (const float*)d_in[1];
    const float* Bw   = (const float*)d_in[2];
    const float* Cw   = (const float*)d_in[3];
    const float* Dv   = (const float*)d_in[4];
    float* y = (float*)d_out;

    float* bt    = (float*)d_ws;                                   // B*L*S    = 65536 floats
    float* btg   = bt  + (size_t)BATCH * SEQ * D_STATE;            // B*L*S    = 65536 floats
    float* carry = btg + (size_t)BATCH * SEQ * D_STATE;            // B*Nc*D*S = 2097152 floats

    hipLaunchKernelGGL(k_bt,    dim3(512), dim3(256), 0, stream, x, Bw, bt, btg);
    hipLaunchKernelGGL(k_scan,  dim3(BATCH * (D_MODEL / 2)), dim3(256), 0, stream, btg, logA, carry);
    hipLaunchKernelGGL(k_final, dim3(BATCH * NCHUNK * (D_MODEL / 256)), dim3(256), 0, stream, x, logA, Cw, Dv, bt, carry, y);
}